// Round 7
// baseline (385.301 us; speedup 1.0000x reference)
//
#include <hip/hip_runtime.h>
#include <hip/hip_bf16.h>

// GraphSAGE 3-layer inference, MI355X.
// R7 (= R6 + compile fix: nontemporal loads must use clang ext-vector type,
// not HIP_vector_type float4).
// Linearity restructure: mean(x[nbr]) @ Wn == mean(x[nbr] @ Wn), so:
//   1. dedup nbr0 -> ascending list of ~161.8k unique nodes (deterministic scan)
//   2. zGEMM: z[p] = bf16(x[list[p]] @ Wneigh0)   (unique rows only, streaming)
//   3. hn[i] = mean_10 z[pos[nbr0[i,f]]]          (512B rows, L3-resident)
//   4. h0 = relu(x[:25600] @ Wself0 + hn + b0)
// Converts 1.05 GB random HBM gather into 0.66 GB near-streaming + 84.9 GF
// extra MFMA (hidden under the stream).

typedef __attribute__((ext_vector_type(4))) float f32x4;
typedef __attribute__((ext_vector_type(8))) short s16x8;

__device__ __forceinline__ unsigned short f2bf_u16(float f) {
  // round-to-nearest-even f32 -> bf16 (finite inputs only)
  unsigned int u = __float_as_uint(f);
  u += 0x7fffu + ((u >> 16) & 1u);
  return (unsigned short)(u >> 16);
}
__device__ __forceinline__ float bf2f(unsigned short u) {
  return __uint_as_float(((unsigned int)u) << 16);
}
__device__ __forceinline__ s16x8 pack_bf16x8(const float4& a, const float4& b) {
  s16x8 w;
  w[0] = (short)f2bf_u16(a.x); w[1] = (short)f2bf_u16(a.y);
  w[2] = (short)f2bf_u16(a.z); w[3] = (short)f2bf_u16(a.w);
  w[4] = (short)f2bf_u16(b.x); w[5] = (short)f2bf_u16(b.y);
  w[6] = (short)f2bf_u16(b.z); w[7] = (short)f2bf_u16(b.w);
  return w;
}
__device__ __forceinline__ s16x8 pack_bf16x8v(f32x4 a, f32x4 b) {
  s16x8 w;
  w[0] = (short)f2bf_u16(a[0]); w[1] = (short)f2bf_u16(a[1]);
  w[2] = (short)f2bf_u16(a[2]); w[3] = (short)f2bf_u16(a[3]);
  w[4] = (short)f2bf_u16(b[0]); w[5] = (short)f2bf_u16(b[1]);
  w[6] = (short)f2bf_u16(b[2]); w[7] = (short)f2bf_u16(b[3]);
  return w;
}
__device__ __forceinline__ void gload16(const void* g, void* l) {
  __builtin_amdgcn_global_load_lds(
      (const __attribute__((address_space(1))) unsigned int*)g,
      (__attribute__((address_space(3))) unsigned int*)l, 16, 0, 0);
}

// ---------- dedup pipeline (deterministic, no atomics) ----------
__global__ __launch_bounds__(256) void zero_flags(unsigned int* flags_u32) {
  int i = blockIdx.x * 256 + threadIdx.x;
  if (i < 64000) flags_u32[i] = 0;  // 256000 bytes
}

__global__ __launch_bounds__(256) void set_flags(const int* __restrict__ nbr0,
                                                 unsigned char* __restrict__ flags) {
  int i = blockIdx.x * 256 + threadIdx.x;  // 1000 x 256 = 256000 entries
  flags[nbr0[i]] = 1;                      // benign same-value races
}

__global__ __launch_bounds__(256) void count_flags(const unsigned char* __restrict__ flags,
                                                   int* __restrict__ bsum) {
  const int b = blockIdx.x, t = threadIdx.x;
  int v = (int)flags[b * 256 + t];
  for (int o = 32; o > 0; o >>= 1) v += __shfl_down(v, o);
  __shared__ int s[4];
  if ((t & 63) == 0) s[t >> 6] = v;
  __syncthreads();
  if (t == 0) bsum[b] = s[0] + s[1] + s[2] + s[3];
}

__global__ __launch_bounds__(1024) void scan_sums(const int* __restrict__ bsum,
                                                  int* __restrict__ offs,
                                                  int* __restrict__ cnt) {
  __shared__ int s[1024];
  const int t = threadIdx.x;
  const int mine = (t < 1000) ? bsum[t] : 0;
  s[t] = mine;
  __syncthreads();
  for (int o = 1; o < 1024; o <<= 1) {
    int v = (t >= o) ? s[t - o] : 0;
    __syncthreads();
    s[t] += v;
    __syncthreads();
  }
  if (t < 1000) offs[t] = s[t] - mine;  // exclusive
  if (t == 999) *cnt = s[999];
}

__global__ __launch_bounds__(256) void scatter_flags(const unsigned char* __restrict__ flags,
                                                     const int* __restrict__ offs,
                                                     int* __restrict__ list,
                                                     int* __restrict__ pos) {
  const int b = blockIdx.x, t = threadIdx.x, n = b * 256 + t;
  const int f = (int)flags[n];
  __shared__ int s[256];
  s[t] = f;
  __syncthreads();
  for (int o = 1; o < 256; o <<= 1) {
    int v = (t >= o) ? s[t - o] : 0;
    __syncthreads();
    s[t] += v;
    __syncthreads();
  }
  if (f) {
    const int p = offs[b] + s[t] - 1;  // ascending positions
    list[p] = n;
    pos[n] = p;
  }
}

// ---------- weight prep: Wts0=Ws0^T, Wtn0=Wn0^T (256x1024), Wt1=[Ws1;Wn1]^T (256x512)
__global__ __launch_bounds__(256) void prep3(
    const float* __restrict__ Ws0, const float* __restrict__ Wn0,
    const float* __restrict__ Ws1, const float* __restrict__ Wn1,
    unsigned short* __restrict__ Wts0, unsigned short* __restrict__ Wtn0,
    unsigned short* __restrict__ Wt1) {
  int idx = blockIdx.x * 256 + threadIdx.x;
  if (idx < 262144) {
    int n = idx >> 10, k = idx & 1023;
    Wts0[idx] = f2bf_u16(Ws0[k * 256 + n]);
  } else if (idx < 524288) {
    int e = idx - 262144, n = e >> 10, k = e & 1023;
    Wtn0[e] = f2bf_u16(Wn0[k * 256 + n]);
  } else {
    int e = idx - 524288;
    if (e < 131072) {
      int n = e >> 9, k = e & 511;
      Wt1[e] = f2bf_u16(k < 256 ? Ws1[k * 256 + n] : Wn1[(k - 256) * 256 + n]);
    }
  }
}

// ---------- GEMM with f32 A (reg-staged convert), K=1024, N=256, BM=64 ----------
// INDIRECT: A rows = x[list[bm+r]], out = z bf16 (no bias). Blocks past *cnt exit.
// !INDIRECT: A rows = x[bm+r], out = relu(acc + hn + bias) f32.
// LDS linear 128B rows; granule XOR-swizzle (g ^ row&7) on write AND read.
// MFMA 16x16x32_bf16; frag row=lane&15, k=8*(lane>>4)+j; C/D col=lane&15, row=(lane>>4)*4+r.
template <bool INDIRECT>
__global__ __launch_bounds__(256) void sage_gemm_f32a(
    const float* __restrict__ X, const int* __restrict__ list,
    const int* __restrict__ cnt_p, const unsigned short* __restrict__ Bt,
    const float* __restrict__ hn, const float* __restrict__ bias,
    unsigned short* __restrict__ Zout, float* __restrict__ Cout) {
  constexpr int BK = 64, Kc = 1024;
  __shared__ __align__(16) unsigned short As[64 * 64];   //  8 KB
  __shared__ __align__(16) unsigned short Bs[256 * 64];  // 32 KB
  const int tid = threadIdx.x, wid = tid >> 6, lane = tid & 63;
  const size_t bm = (size_t)blockIdx.x * 64;
  int cnt = 0;
  if (INDIRECT) {
    cnt = *cnt_p;
    if ((int)bm >= cnt) return;
  }

  // A staging: 4 threads/row, 16 f32 (4x f32x4) each
  const int arow = tid >> 2, afc = (tid & 3) * 16;
  size_t asrc;
  if (INDIRECT) {
    const int li = (int)bm + arow;
    asrc = (size_t)((li < cnt) ? list[li] : list[0]);
  } else {
    asrc = bm + arow;
  }
  const float* gA = X + asrc * Kc + afc;
  const int g0 = ((tid & 3) * 2) ^ (arow & 7);  // swizzled granule for 1st 8 bf16
  unsigned short* wA = As + arow * 64;

  // B staging via global_load_lds (granule pre-swizzle on source)
  const int srow = (wid << 3) + (lane >> 3);
  const int gs = (lane & 7) ^ ((lane >> 3) & 7);
  const unsigned short* gB = Bt + (size_t)srow * Kc + gs * 8;
  unsigned short* lB = Bs + wid * 512;

  f32x4 acc[4][4];
#pragma unroll
  for (int mi = 0; mi < 4; ++mi)
#pragma unroll
    for (int ni = 0; ni < 4; ++ni) acc[mi][ni] = (f32x4){0.f, 0.f, 0.f, 0.f};

  const int l15 = lane & 15, lq = lane >> 4, l7 = lane & 7;

  // prologue: A-tile 0 into regs (nontemporal: keep z/L3 unpolluted)
  const f32x4* p0 = reinterpret_cast<const f32x4*>(gA);
  f32x4 a0 = __builtin_nontemporal_load(p0 + 0);
  f32x4 a1 = __builtin_nontemporal_load(p0 + 1);
  f32x4 a2 = __builtin_nontemporal_load(p0 + 2);
  f32x4 a3 = __builtin_nontemporal_load(p0 + 3);

  for (int kt = 0; kt < Kc; kt += BK) {
#pragma unroll
    for (int p = 0; p < 8; ++p) gload16(gB + p * 32 * (size_t)Kc + kt, lB + p * 2048);
    *reinterpret_cast<s16x8*>(wA + g0 * 8) = pack_bf16x8v(a0, a1);
    *reinterpret_cast<s16x8*>(wA + (g0 ^ 1) * 8) = pack_bf16x8v(a2, a3);
    __syncthreads();
    if (kt + BK < Kc) {  // prefetch next A-tile; overlaps MFMA below
      const f32x4* pn = reinterpret_cast<const f32x4*>(gA + kt + BK);
      a0 = __builtin_nontemporal_load(pn + 0);
      a1 = __builtin_nontemporal_load(pn + 1);
      a2 = __builtin_nontemporal_load(pn + 2);
      a3 = __builtin_nontemporal_load(pn + 3);
    }
#pragma unroll
    for (int ks = 0; ks < 2; ++ks) {
      const int gr = ((ks << 2) + lq) ^ l7;
      s16x8 af[4], bf_[4];
#pragma unroll
      for (int mi = 0; mi < 4; ++mi)
        af[mi] = *reinterpret_cast<const s16x8*>(
            reinterpret_cast<const char*>(As) + (mi * 16 + l15) * 128 + gr * 16);
#pragma unroll
      for (int ni = 0; ni < 4; ++ni)
        bf_[ni] = *reinterpret_cast<const s16x8*>(
            reinterpret_cast<const char*>(Bs) + (wid * 64 + ni * 16 + l15) * 128 + gr * 16);
#pragma unroll
      for (int mi = 0; mi < 4; ++mi)
#pragma unroll
        for (int ni = 0; ni < 4; ++ni)
          acc[mi][ni] = __builtin_amdgcn_mfma_f32_16x16x32_bf16(af[mi], bf_[ni], acc[mi][ni], 0, 0, 0);
    }
    __syncthreads();
  }

#pragma unroll
  for (int mi = 0; mi < 4; ++mi) {
    const size_t r0 = bm + mi * 16 + lq * 4;
#pragma unroll
    for (int ni = 0; ni < 4; ++ni) {
      const int c = wid * 64 + ni * 16 + l15;
      if (INDIRECT) {
#pragma unroll
        for (int rr = 0; rr < 4; ++rr)
          Zout[(r0 + rr) * 256 + c] = f2bf_u16(acc[mi][ni][rr]);
      } else {
        const float bv = bias[c];
#pragma unroll
        for (int rr = 0; rr < 4; ++rr) {
          float v = acc[mi][ni][rr] + hn[(r0 + rr) * 256 + c] + bv;
          Cout[(r0 + rr) * 256 + c] = fmaxf(v, 0.f);
        }
      }
    }
  }
}

// ---------- hn[i] = mean_10 z[pos[nbr0[i,f]]]  (z bf16, L3-resident) ----------
__global__ __launch_bounds__(64) void gather_mean_z(
    const unsigned short* __restrict__ z, const int* __restrict__ nbr,
    const int* __restrict__ pos, float* __restrict__ hn) {
  const int i = blockIdx.x, t = threadIdx.x;  // 64 threads x 4 cols
  float4 a = make_float4(0.f, 0.f, 0.f, 0.f);
#pragma unroll
  for (int f = 0; f < 10; ++f) {
    const int p = pos[nbr[i * 10 + f]];
    ushort4 u = *reinterpret_cast<const ushort4*>(z + (size_t)p * 256 + t * 4);
    a.x += bf2f(u.x); a.y += bf2f(u.y); a.z += bf2f(u.z); a.w += bf2f(u.w);
  }
  a.x *= 0.1f; a.y *= 0.1f; a.z *= 0.1f; a.w *= 0.1f;
  *reinterpret_cast<float4*>(hn + (size_t)i * 256 + t * 4) = a;
}

// ---------- layer-1 gather (unchanged) ----------
template <int D, int F>
__global__ void gather_cat(const float* __restrict__ h, const int* __restrict__ nbr,
                           unsigned short* __restrict__ out) {
  const int i = blockIdx.x;
  const int c = threadIdx.x;
  int idx[F];
#pragma unroll
  for (int f = 0; f < F; ++f) idx[f] = nbr[(size_t)i * F + f];
  constexpr float inv = 1.0f / (float)F;
  float4 s = reinterpret_cast<const float4*>(h + (size_t)i * D)[c];
  ushort4 us = {f2bf_u16(s.x), f2bf_u16(s.y), f2bf_u16(s.z), f2bf_u16(s.w)};
  reinterpret_cast<ushort4*>(out + (size_t)i * 2 * D)[c] = us;
  float ax = 0.f, ay = 0.f, az = 0.f, aw = 0.f;
#pragma unroll
  for (int f = 0; f < F; ++f) {
    float4 v = reinterpret_cast<const float4*>(h + (size_t)idx[f] * D)[c];
    ax += v.x; ay += v.y; az += v.z; aw += v.w;
  }
  ushort4 un = {f2bf_u16(ax * inv), f2bf_u16(ay * inv), f2bf_u16(az * inv), f2bf_u16(aw * inv)};
  reinterpret_cast<ushort4*>(out + (size_t)i * 2 * D + D)[c] = un;
}

// ---------- m97-class bf16 GEMM (layer 1), unchanged from R5 ----------
template <bool RELU>
__global__ __launch_bounds__(256) void gemm_gl(
    const unsigned short* __restrict__ A, const unsigned short* __restrict__ Bt,
    const float* __restrict__ bias, float* __restrict__ C, int Kc) {
  __shared__ __align__(16) unsigned short As[64 * 64];
  __shared__ __align__(16) unsigned short Bs[256 * 64];
  const int tid = threadIdx.x, wid = tid >> 6, lane = tid & 63;
  const size_t bm = (size_t)blockIdx.x * 64;
  const int srow = (wid << 3) + (lane >> 3);
  const int gs = (lane & 7) ^ ((lane >> 3) & 7);
  const unsigned short* gA = A + (bm + srow) * (size_t)Kc + gs * 8;
  const unsigned short* gB = Bt + (size_t)srow * Kc + gs * 8;
  unsigned short* lA = As + wid * 512;
  unsigned short* lB = Bs + wid * 512;
  f32x4 acc[4][4];
#pragma unroll
  for (int mi = 0; mi < 4; ++mi)
#pragma unroll
    for (int ni = 0; ni < 4; ++ni) acc[mi][ni] = (f32x4){0.f, 0.f, 0.f, 0.f};
  const int l15 = lane & 15, lq = lane >> 4, l7 = lane & 7;
  for (int kt = 0; kt < Kc; kt += 64) {
    gload16(gA + kt, lA);
    gload16(gA + 32 * (size_t)Kc + kt, lA + 2048);
#pragma unroll
    for (int p = 0; p < 8; ++p) gload16(gB + p * 32 * (size_t)Kc + kt, lB + p * 2048);
    __syncthreads();
#pragma unroll
    for (int ks = 0; ks < 2; ++ks) {
      const int gr = ((ks << 2) + lq) ^ l7;
      s16x8 af[4], bf_[4];
#pragma unroll
      for (int mi = 0; mi < 4; ++mi)
        af[mi] = *reinterpret_cast<const s16x8*>(
            reinterpret_cast<const char*>(As) + (mi * 16 + l15) * 128 + gr * 16);
#pragma unroll
      for (int ni = 0; ni < 4; ++ni)
        bf_[ni] = *reinterpret_cast<const s16x8*>(
            reinterpret_cast<const char*>(Bs) + (wid * 64 + ni * 16 + l15) * 128 + gr * 16);
#pragma unroll
      for (int mi = 0; mi < 4; ++mi)
#pragma unroll
        for (int ni = 0; ni < 4; ++ni)
          acc[mi][ni] = __builtin_amdgcn_mfma_f32_16x16x32_bf16(af[mi], bf_[ni], acc[mi][ni], 0, 0, 0);
    }
    __syncthreads();
  }
#pragma unroll
  for (int mi = 0; mi < 4; ++mi) {
    const size_t r0 = bm + mi * 16 + lq * 4;
#pragma unroll
    for (int ni = 0; ni < 4; ++ni) {
      const int c = wid * 64 + ni * 16 + l15;
      const float bv = bias[c];
#pragma unroll
      for (int rr = 0; rr < 4; ++rr) {
        float v = acc[mi][ni][rr] + bv;
        if (RELU) v = fmaxf(v, 0.f);
        C[(r0 + rr) * 256 + c] = v;
      }
    }
  }
}

// ---------- final layer (unchanged) ----------
__global__ void out_fused(const float* __restrict__ h1, const int* __restrict__ nbr,
                          const float* __restrict__ Ws, const float* __restrict__ Wn,
                          const float* __restrict__ b, float* __restrict__ out) {
  const int i = blockIdx.x, t = threadIdx.x;
  __shared__ float row[512];
  __shared__ float part[8][32];
  row[t] = h1[(size_t)i * 256 + t];
  float s = 0.f;
#pragma unroll
  for (int f = 0; f < 5; ++f) s += h1[(size_t)nbr[i * 5 + f] * 256 + t];
  row[256 + t] = s * 0.2f;
  __syncthreads();
  const int n = t & 31, seg = t >> 5;
  float p = 0.f;
  if (n < 19) {
#pragma unroll
    for (int e = 0; e < 64; ++e) {
      const int k = seg * 64 + e;
      const float w = (k < 256) ? Ws[k * 19 + n] : Wn[(k - 256) * 19 + n];
      p += row[k] * w;
    }
  }
  part[seg][n] = p;
  __syncthreads();
  if (t < 19) {
    float sm = b[t];
#pragma unroll
    for (int g = 0; g < 8; ++g) sm += part[g][t];
    out[(size_t)i * 19 + t] = sm;
  }
}

extern "C" void kernel_launch(void* const* d_in, const int* in_sizes, int n_in,
                              void* d_out, int out_size, void* d_ws, size_t ws_size,
                              hipStream_t stream) {
  const float* x    = (const float*)d_in[0];
  const int*   nbr0 = (const int*)d_in[1];
  const int*   nbr1 = (const int*)d_in[2];
  const int*   nbr2 = (const int*)d_in[3];
  const float* Ws0  = (const float*)d_in[4];
  const float* Wn0  = (const float*)d_in[5];
  const float* b0   = (const float*)d_in[6];
  const float* Ws1  = (const float*)d_in[7];
  const float* Wn1  = (const float*)d_in[8];
  const float* b1   = (const float*)d_in[9];
  const float* Ws2  = (const float*)d_in[10];
  const float* Wn2  = (const float*)d_in[11];
  const float* b2   = (const float*)d_in[12];
  float* out = (float*)d_out;

  char* ws = (char*)d_ws;
  unsigned char* flags = (unsigned char*)(ws);                //    262144
  int*  bsum = (int*)(ws + 262144);                           //      4096
  int*  offs = (int*)(ws + 266240);                           //      4096
  int*  cnt  = (int*)(ws + 270336);                           //       256
  int*  list = (int*)(ws + 270592);                           //   1024000
  int*  pos  = (int*)(ws + 1294592);                          //   1024000
  unsigned short* z    = (unsigned short*)(ws + 2318592);     // 131072000
  float*          hn   = (float*)(ws + 133390592);            //  26214400
  float*          h0   = (float*)(ws + 159604992);            //  26214400
  unsigned short* Wts0 = (unsigned short*)(ws + 185819392);   //    524288
  unsigned short* Wtn0 = (unsigned short*)(ws + 186343680);   //    524288
  unsigned short* Wt1  = (unsigned short*)(ws + 186867968);   //    262144
  unsigned short* cat1 = (unsigned short*)(ws + 187130112);   //   2621440
  float*          h1   = (float*)(ws + 189751552);            //   2621440
  // total ws use: ~192.4 MB

  prep3<<<2560, 256, 0, stream>>>(Ws0, Wn0, Ws1, Wn1, Wts0, Wtn0, Wt1);
  zero_flags<<<250, 256, 0, stream>>>((unsigned int*)flags);
  set_flags<<<1000, 256, 0, stream>>>(nbr0, flags);
  count_flags<<<1000, 256, 0, stream>>>(flags, bsum);
  scan_sums<<<1, 1024, 0, stream>>>(bsum, offs, cnt);
  scatter_flags<<<1000, 256, 0, stream>>>(flags, offs, list, pos);

  // z[p] = bf16(x[list[p]] @ Wn0); grid covers worst case 256000/64
  sage_gemm_f32a<true><<<4000, 256, 0, stream>>>(x, list, cnt, Wtn0,
                                                 nullptr, nullptr, z, nullptr);
  gather_mean_z<<<25600, 64, 0, stream>>>(z, nbr0, pos, hn);
  // h0 = relu(x[:25600] @ Ws0 + hn + b0)
  sage_gemm_f32a<false><<<400, 256, 0, stream>>>(x, nullptr, nullptr, Wts0,
                                                 hn, b0, nullptr, h0);

  gather_cat<256, 10><<<2560, 64, 0, stream>>>(h0, nbr1, cat1);
  gemm_gl<true><<<40, 256, 0, stream>>>(cat1, Wt1, b1, h1, 512);
  out_fused<<<512, 256, 0, stream>>>(h1, nbr2, Ws2, Wn2, b2, out);
}

// Round 8
// 287.620 us; speedup vs baseline: 1.3396x; 1.3396x over previous
//
#include <hip/hip_runtime.h>
#include <hip/hip_bf16.h>

// GraphSAGE 3-layer inference, MI355X.
// R8 = R5 revert (R6/R7 dedup+linearity restructure was net -93us: K-tiled
// 256B-granule random reads have ~16x the DRAM page activations of R5's
// one-4KB-burst-per-row gather) + h0 stored bf16 (halves gather1 traffic).
//
// Pipeline (5 launches):
//   gather0_prep       : A0 = [bf16(x_self)|bf16(mean nbr0)] + Wt0/Wt1 prep
//   gemm_gl<relu,bf16> : h0b = bf16(relu(A0 @ Wt0^T + b0))     (25600 x 256)
//   gather_cat_bf16    : cat1 = [h0b | bf16(mean_10 h0b)]      (2560 x 512)
//   gemm_gl<relu,f32>  : h1 = relu(cat1 @ Wt1^T + b1)          (2560 x 256 f32)
//   out_fused          : out = [h1|mean_5 h1] @ [Ws2;Wn2] + b2 (512 x 19 f32)

typedef __attribute__((ext_vector_type(4))) float f32x4;
typedef __attribute__((ext_vector_type(8))) short s16x8;

__device__ __forceinline__ unsigned short f2bf_u16(float f) {
  // round-to-nearest-even f32 -> bf16 (finite inputs only)
  unsigned int u = __float_as_uint(f);
  u += 0x7fffu + ((u >> 16) & 1u);
  return (unsigned short)(u >> 16);
}
__device__ __forceinline__ float bf2f(unsigned short u) {
  return __uint_as_float(((unsigned int)u) << 16);
}
__device__ __forceinline__ s16x8 pack_bf16x8(const float4& a, const float4& b) {
  s16x8 w;
  w[0] = (short)f2bf_u16(a.x); w[1] = (short)f2bf_u16(a.y);
  w[2] = (short)f2bf_u16(a.z); w[3] = (short)f2bf_u16(a.w);
  w[4] = (short)f2bf_u16(b.x); w[5] = (short)f2bf_u16(b.y);
  w[6] = (short)f2bf_u16(b.z); w[7] = (short)f2bf_u16(b.w);
  return w;
}
__device__ __forceinline__ void gload16(const void* g, void* l) {
  // global -> LDS DMA, 16B per lane. LDS dest = wave-uniform base + lane*16.
  __builtin_amdgcn_global_load_lds(
      (const __attribute__((address_space(1))) unsigned int*)g,
      (__attribute__((address_space(3))) unsigned int*)l, 16, 0, 0);
}

// Layer-0 gather (+ fused weight prep in tail blocks).
// Blocks [0, NDST): one dst node each, 128 threads, 8 floats/thread.
//   A0 row = [bf16(x[i]) | bf16(mean_10 x[nbr[i]])], 16B nontemporal stores
//   (A0 is read once by gemm0 and >L2; keep L3 free for x's random rows).
// Blocks [NDST, NDST+40): grid-stride weight prep for Wt0 (256x2048) and
//   Wt1 (256x512): Wt[n][k] = bf16([Wself;Wneigh]^T). Transposed reads, but
//   the W tables are ~1MB -> L2-absorbed.
__global__ __launch_bounds__(128) void gather0_prep(
    const float* __restrict__ x, const int* __restrict__ nbr,
    unsigned short* __restrict__ A0,
    const float* __restrict__ Ws0, const float* __restrict__ Wn0,
    unsigned short* __restrict__ Wt0,
    const float* __restrict__ Ws1, const float* __restrict__ Wn1,
    unsigned short* __restrict__ Wt1) {
  constexpr int NDST = 25600, D = 1024, F = 10;
  const int bid = blockIdx.x, t = threadIdx.x;

  if (bid < NDST) {
    const size_t i = bid;
    int idx[F];
#pragma unroll
    for (int f = 0; f < F; ++f) idx[f] = nbr[i * F + f];

    // self: floats [8t, 8t+8)
    const float4* ps = reinterpret_cast<const float4*>(x + i * D) + 2 * t;
    float4 s0 = ps[0], s1 = ps[1];
    __builtin_nontemporal_store(
        pack_bf16x8(s0, s1), reinterpret_cast<s16x8*>(A0 + i * 2 * D) + t);

    // neighbor mean
    float4 a0 = make_float4(0.f, 0.f, 0.f, 0.f);
    float4 a1 = make_float4(0.f, 0.f, 0.f, 0.f);
#pragma unroll
    for (int f = 0; f < F; ++f) {
      const float4* p = reinterpret_cast<const float4*>(x + (size_t)idx[f] * D) + 2 * t;
      float4 u0 = p[0], u1 = p[1];
      a0.x += u0.x; a0.y += u0.y; a0.z += u0.z; a0.w += u0.w;
      a1.x += u1.x; a1.y += u1.y; a1.z += u1.z; a1.w += u1.w;
    }
    constexpr float inv = 1.0f / (float)F;
    a0.x *= inv; a0.y *= inv; a0.z *= inv; a0.w *= inv;
    a1.x *= inv; a1.y *= inv; a1.z *= inv; a1.w *= inv;
    __builtin_nontemporal_store(
        pack_bf16x8(a0, a1), reinterpret_cast<s16x8*>(A0 + i * 2 * D + D) + t);
  } else {
    const int pt = (bid - NDST) * 128 + t;  // 0..5119
    for (int e = pt; e < 256 * 2048; e += 5120) {
      int n = e >> 11, k = e & 2047;
      float v = (k < 1024) ? Ws0[k * 256 + n] : Wn0[(k - 1024) * 256 + n];
      Wt0[e] = f2bf_u16(v);
    }
    for (int e = pt; e < 256 * 512; e += 5120) {
      int n = e >> 9, k = e & 511;
      float v = (k < 256) ? Ws1[k * 256 + n] : Wn1[(k - 256) * 256 + n];
      Wt1[e] = f2bf_u16(v);
    }
  }
}

// Layer-1 gather, bf16 input: cat1 = [h0b[i] | bf16(mean_10 h0b[nbr1[i]])].
// 64 threads, 4 bf16 (8B) per thread; h0b (13MB) is L2/L3-resident.
__global__ __launch_bounds__(64) void gather_cat_bf16(
    const unsigned short* __restrict__ h, const int* __restrict__ nbr,
    unsigned short* __restrict__ out) {
  constexpr int D = 256, F = 10;
  const int i = blockIdx.x, t = threadIdx.x;
  int idx[F];
#pragma unroll
  for (int f = 0; f < F; ++f) idx[f] = nbr[(size_t)i * F + f];

  // self half: direct bf16 copy
  ushort4 s = reinterpret_cast<const ushort4*>(h + (size_t)i * D)[t];
  reinterpret_cast<ushort4*>(out + (size_t)i * 2 * D)[t] = s;

  float ax = 0.f, ay = 0.f, az = 0.f, aw = 0.f;
#pragma unroll
  for (int f = 0; f < F; ++f) {
    ushort4 u = reinterpret_cast<const ushort4*>(h + (size_t)idx[f] * D)[t];
    ax += bf2f(u.x); ay += bf2f(u.y); az += bf2f(u.z); aw += bf2f(u.w);
  }
  constexpr float inv = 1.0f / (float)F;
  ushort4 un = {f2bf_u16(ax * inv), f2bf_u16(ay * inv), f2bf_u16(az * inv), f2bf_u16(aw * inv)};
  reinterpret_cast<ushort4*>(out + (size_t)i * 2 * D + D)[t] = un;
}

// m97-class GEMM: C[m][n] = act(sum_k A[m][k]*Bt[n][k] + bias[n]).
// Fixed: BM=64, BN=N=256, BK=64, 256 threads = 4 waves, wave tile 64x64.
// Staging via global_load_lds dwordx4 into LINEAR LDS [row][64] bf16;
// bank conflicts killed by granule XOR-swizzle applied on BOTH the global
// source (gs) and the ds_read side (gr) — rule 21.
// MFMA 16x16x32_bf16; A/B frag: row=lane&15, k=8*(lane>>4)+j;
// C/D frag: col=lane&15, row=(lane>>4)*4+r.
template <bool RELU, bool OUTBF>
__global__ __launch_bounds__(256) void gemm_gl(
    const unsigned short* __restrict__ A,   // [M][Kc] bf16 row-major
    const unsigned short* __restrict__ Bt,  // [256][Kc] bf16 row-major
    const float* __restrict__ bias,         // [256]
    void* __restrict__ Cout,                // [M][256] f32 or bf16 per OUTBF
    int Kc) {
  constexpr int BM = 64, BN = 256, BK = 64;
  __shared__ __align__(16) unsigned short As[BM * BK];  //  8 KB
  __shared__ __align__(16) unsigned short Bs[BN * BK];  // 32 KB

  const int tid = threadIdx.x;
  const int wid = tid >> 6, lane = tid & 63;
  const size_t bm = (size_t)blockIdx.x * BM;

  const int srow = (wid << 3) + (lane >> 3);            // 0..31 per pass
  const int gs = (lane & 7) ^ ((lane >> 3) & 7);        // src granule (inverse swz)
  const unsigned short* gA = A + (bm + srow) * (size_t)Kc + gs * 8;
  const unsigned short* gB = Bt + (size_t)srow * Kc + gs * 8;
  unsigned short* lA = As + wid * 512;  // wave-uniform
  unsigned short* lB = Bs + wid * 512;

  f32x4 acc[4][4];
#pragma unroll
  for (int mi = 0; mi < 4; ++mi)
#pragma unroll
    for (int ni = 0; ni < 4; ++ni)
      acc[mi][ni] = (f32x4){0.f, 0.f, 0.f, 0.f};

  const int l15 = lane & 15, lq = lane >> 4, l7 = lane & 7;

  for (int kt = 0; kt < Kc; kt += BK) {
    gload16(gA + kt, lA);
    gload16(gA + 32 * (size_t)Kc + kt, lA + 2048);
#pragma unroll
    for (int p = 0; p < 8; ++p)
      gload16(gB + p * 32 * (size_t)Kc + kt, lB + p * 2048);
    __syncthreads();  // compiler drains vmcnt(0) before barrier

#pragma unroll
    for (int ks = 0; ks < 2; ++ks) {
      const int gr = ((ks << 2) + lq) ^ l7;  // swizzled granule for frag reads
      s16x8 af[4], bf_[4];
#pragma unroll
      for (int mi = 0; mi < 4; ++mi) {
        const int row = mi * 16 + l15;
        af[mi] = *reinterpret_cast<const s16x8*>(
            reinterpret_cast<const char*>(As) + row * 128 + gr * 16);
      }
#pragma unroll
      for (int ni = 0; ni < 4; ++ni) {
        const int row = wid * 64 + ni * 16 + l15;
        bf_[ni] = *reinterpret_cast<const s16x8*>(
            reinterpret_cast<const char*>(Bs) + row * 128 + gr * 16);
      }
#pragma unroll
      for (int mi = 0; mi < 4; ++mi)
#pragma unroll
        for (int ni = 0; ni < 4; ++ni)
          acc[mi][ni] = __builtin_amdgcn_mfma_f32_16x16x32_bf16(af[mi], bf_[ni], acc[mi][ni], 0, 0, 0);
    }
    __syncthreads();
  }

#pragma unroll
  for (int mi = 0; mi < 4; ++mi) {
    const size_t r0 = bm + mi * 16 + lq * 4;
#pragma unroll
    for (int ni = 0; ni < 4; ++ni) {
      const int c = wid * 64 + ni * 16 + l15;
      const float bv = bias[c];
#pragma unroll
      for (int rr = 0; rr < 4; ++rr) {
        float v = acc[mi][ni][rr] + bv;
        if (RELU) v = fmaxf(v, 0.f);
        if (OUTBF)
          ((unsigned short*)Cout)[(r0 + rr) * (size_t)BN + c] = f2bf_u16(v);
        else
          ((float*)Cout)[(r0 + rr) * (size_t)BN + c] = v;
      }
    }
  }
}

// Final layer fused: row = [h1[i] | mean_5 h1[nbr2[i]]], out = row @ [Ws2;Wn2] + b2
__global__ void out_fused(const float* __restrict__ h1, const int* __restrict__ nbr,
                          const float* __restrict__ Ws, const float* __restrict__ Wn,
                          const float* __restrict__ b, float* __restrict__ out) {
  const int i = blockIdx.x, t = threadIdx.x;  // 256 threads
  __shared__ float row[512];
  __shared__ float part[8][32];
  row[t] = h1[(size_t)i * 256 + t];
  float s = 0.f;
#pragma unroll
  for (int f = 0; f < 5; ++f) s += h1[(size_t)nbr[i * 5 + f] * 256 + t];
  row[256 + t] = s * 0.2f;
  __syncthreads();
  const int n = t & 31, seg = t >> 5;  // 8 segments x 64 k-elems
  float p = 0.f;
  if (n < 19) {
#pragma unroll
    for (int e = 0; e < 64; ++e) {
      const int k = seg * 64 + e;
      const float w = (k < 256) ? Ws[k * 19 + n] : Wn[(k - 256) * 19 + n];
      p += row[k] * w;
    }
  }
  part[seg][n] = p;
  __syncthreads();
  if (t < 19) {
    float sm = b[t];
#pragma unroll
    for (int g = 0; g < 8; ++g) sm += part[g][t];
    out[(size_t)i * 19 + t] = sm;
  }
}

extern "C" void kernel_launch(void* const* d_in, const int* in_sizes, int n_in,
                              void* d_out, int out_size, void* d_ws, size_t ws_size,
                              hipStream_t stream) {
  const float* x    = (const float*)d_in[0];
  const int*   nbr0 = (const int*)d_in[1];
  const int*   nbr1 = (const int*)d_in[2];
  const int*   nbr2 = (const int*)d_in[3];
  const float* Ws0  = (const float*)d_in[4];
  const float* Wn0  = (const float*)d_in[5];
  const float* b0   = (const float*)d_in[6];
  const float* Ws1  = (const float*)d_in[7];
  const float* Wn1  = (const float*)d_in[8];
  const float* b1   = (const float*)d_in[9];
  const float* Ws2  = (const float*)d_in[10];
  const float* Wn2  = (const float*)d_in[11];
  const float* b2   = (const float*)d_in[12];
  float* out = (float*)d_out;

  char* ws = (char*)d_ws;
  unsigned short* A0   = (unsigned short*)(ws);                 // 25600*2048*2 = 104857600
  unsigned short* Wt0  = (unsigned short*)(ws + 104857600);     // 256*2048*2   =   1048576
  unsigned short* h0b  = (unsigned short*)(ws + 105906176);     // 25600*256*2  =  13107200
  unsigned short* cat1 = (unsigned short*)(ws + 119013376);     // 2560*512*2   =   2621440
  unsigned short* Wt1  = (unsigned short*)(ws + 121634816);     // 256*512*2    =    262144
  float*          h1   = (float*)(ws + 121896960);              // 2560*256*4   =   2621440
  // total ws use: ~124.5 MB

  gather0_prep<<<25600 + 40, 128, 0, stream>>>(x, nbr0, A0, Ws0, Wn0, Wt0, Ws1, Wn1, Wt1);
  gemm_gl<true, true><<<400, 256, 0, stream>>>(A0, Wt0, b0, h0b, 2048);

  gather_cat_bf16<<<2560, 64, 0, stream>>>(h0b, nbr1, cat1);
  gemm_gl<true, false><<<40, 256, 0, stream>>>(cat1, Wt1, b1, h1, 512);

  out_fused<<<512, 256, 0, stream>>>(h1, nbr2, Ws2, Wn2, b2, out);
}